// Round 2
// 92.561 us; speedup vs baseline: 1.1614x; 1.1614x over previous
//
#include <hip/hip_runtime.h>

// BilateralFilter3D 3x3x3, replicate pad, sigma_d=120, sigma_r=1.2
// (B,1,128,192,192) fp32.
//
// Round 8 == Round 7 retry (previous bench died with "MI355X container
// failed twice" -- infra, no kernel verdict). One cosmetic hardening: NN is
// zero-initialized so no path can read an uninitialized register.
//
// Round 7 theory (unchanged): v6 was VALU-issue-bound: 42.6us kernel,
// VALUBusy 56% -> 23.8us busy == the 27-neighbor math floor (~162 VALU
// inst/voxel); HBM only 19%. Latency-side fixes can't go below the busy
// floor, so shrink the math itself:
//   w = A0 + A1*d^2 + A2*d^4  (d = n - c) is polynomial in n and c, so
//   num/den reduce to box power sums S_k = sum n^k (k=1..5):
//     den = 27A0 + A1*(S2-2c*S1+27c^2) + A2*(S4-4c*S3+6c^2*S2-4c^3*S1+27c^4)
//     num = A0*S1 + A1*(S3-2c*S2+c^2*S1) + A2*(S5-4c*S4+6c^2*S3-4c^3*S2+c^4*S1)
//   Box sums are SEPARABLE: x-tap -> y-sum -> z-sum. Exact same weight
//   polynomial as v6, only reassociated (error ~1e-5 on den>=19).
// Layout: 64 lanes x 3 voxels = one full 192-row per wave; x-neighbors of the
// y-summed power rows cross lanes via __shfl (wave-aligned rows -> no
// wave-boundary hole, boundary lanes replicate via cndmask). Per-plane
// partials (5 f3 power sums) are computed once, reused by 3 outputs via the
// rotating 3-plane window; ZC=8 amortizes the 3-plane preamble.
// Predicted: ~92 VALU inst/voxel -> busy ~13-15us; kernel 42.6 -> 25-30us,
// hbm ~2.5 TB/s, VGPR ~100-130, absmax unchanged.

typedef float f3 __attribute__((ext_vector_type(3)));

constexpr int Dd = 128;
constexpr int Hh = 192;
constexpr int Ww = 192;
constexpr int ZC = 8;                 // z-steps per block

// quadratic minimax for exp(-t/(2*1.2^2)), t in [0,1]; spatial weights
// (dev <= 1.05e-4 from 1) folded out entirely. Same coefficients as v6.
constexpr float A0 = 0.9998131f;
constexpr float A1 = -0.3437852f;
constexpr float A2 = 0.0508019f;

__device__ __forceinline__ f3 splat3(float v) { return (f3){v, v, v}; }
__device__ __forceinline__ f3 fma3(f3 a, f3 b, f3 c) {
    return __builtin_elementwise_fma(a, b, c);
}
__device__ __forceinline__ f3 fmas(f3 a, float b, f3 c) {
    return __builtin_elementwise_fma(a, splat3(b), c);
}

struct PS { f3 s1, s2, s3, s4, s5; };   // x-tapped, y-summed power sums

__global__ __launch_bounds__(256, 2)
void bilateral3d_v8(const float* __restrict__ vol, float* __restrict__ out)
{
    const int t  = threadIdx.x;              // lane 0..63 (== wave lane)
    const int ty = threadIdx.y;              // 0..3
    const int h  = (blockIdx.x << 2) + ty;   // 0..191
    const int z0 = blockIdx.y * ZC;          // 0,8,...,120
    const int b  = blockIdx.z;

    const size_t plane = (size_t)Hh * Ww;
    const float* __restrict__ base  = vol + (size_t)b * Dd * plane;
    float* __restrict__       obase = out + (size_t)b * Dd * plane;

    const int x0  = t * 3;                   // 3 voxels per lane, 64*3 = 192
    const int yy0 = (h > 0) ? h - 1 : 0;     // replicate via index clamp
    const int yy2 = (h < Hh - 1) ? h + 1 : Hh - 1;

    auto load_rows = [&](f3 dst[3], int z) {
        const float* __restrict__ zb = base + (size_t)z * plane + x0;
        const float* r0 = zb + (size_t)yy0 * Ww;
        const float* r1 = zb + (size_t)h   * Ww;
        const float* r2 = zb + (size_t)yy2 * Ww;
        dst[0] = (f3){r0[0], r0[1], r0[2]};
        dst[1] = (f3){r1[0], r1[1], r1[2]};
        dst[2] = (f3){r2[0], r2[1], r2[2]};
    };

    // x-tap with lane-crossing neighbors on a y-summed power row v.
    // u.x = v(x-1)+v(x)+v(x+1) etc.; lane 0 / 63 replicate (clamp).
#define XTAP(vk, ok)                                                          \
    do {                                                                      \
        f3 v = (vk);                                                          \
        float L = __shfl_up(v.z, 1);                                          \
        float R = __shfl_down(v.x, 1);                                        \
        L = (t == 0)  ? v.x : L;                                              \
        R = (t == 63) ? v.z : R;                                              \
        float t1 = v.x + v.y;                                                 \
        float t2 = v.y + v.z;                                                 \
        (ok) = (f3){L + t1, t1 + v.z, t2 + R};                                \
    } while (0)

    // raw 3 rows of one z-plane -> y+x collapsed power sums (5 f3)
    auto process = [&](const f3 r[3], PS& o) {
        f3 p2a = r[0] * r[0], p2b = r[1] * r[1], p2c = r[2] * r[2];
        f3 p3a = p2a * r[0], p3b = p2b * r[1], p3c = p2c * r[2];
        f3 p4a = p2a * p2a, p4b = p2b * p2b, p4c = p2c * p2c;
        f3 p5a = p4a * r[0], p5b = p4b * r[1], p5c = p4c * r[2];
        f3 v1 = r[0] + r[1] + r[2];
        f3 v2 = p2a + p2b + p2c;
        f3 v3 = p3a + p3b + p3c;
        f3 v4 = p4a + p4b + p4c;
        f3 v5 = p5a + p5b + p5c;
        XTAP(v1, o.s1);
        XTAP(v2, o.s2);
        XTAP(v3, o.s3);
        XTAP(v4, o.s4);
        XTAP(v5, o.s5);
    };

    PS P0, P1, P2;           // planes z-1, z, z+1
    f3 cenB, cenC;           // raw center rows of planes z, z+1
    f3 NR[3];                // raw rows of plane z+2 (in flight -> next step)
    {
        f3 Ra[3], Rb[3], Rc[3];
        load_rows(Ra, (z0 > 0) ? z0 - 1 : 0);
        load_rows(Rb, z0);
        load_rows(Rc, (z0 + 1 < Dd) ? z0 + 1 : Dd - 1);
        load_rows(NR, (z0 + 2 < Dd) ? z0 + 2 : Dd - 1);
        __builtin_amdgcn_sched_barrier(0);   // keep preamble loads batched
        process(Ra, P0);
        process(Rb, P1);
        process(Rc, P2);
        cenB = Rb[1];
        cenC = Rc[1];
    }

#pragma unroll
    for (int dz = 0; dz < ZC; ++dz) {
        const int z = z0 + dz;

        // issue loads for plane z+3 now; consumed NEXT iteration -> one full
        // iteration (~500+ cyc of combine+process) of latency cover.
        f3 NN[3] = { splat3(0.f), splat3(0.f), splat3(0.f) };
        if (dz < ZC - 1) {
            load_rows(NN, (z + 3 < Dd) ? z + 3 : Dd - 1);
            __builtin_amdgcn_sched_barrier(0);
        }

        // ---- combine: z-sum the plane partials, Horner in c, write out ----
        f3 S1 = P0.s1 + P1.s1 + P2.s1;
        f3 S2 = P0.s2 + P1.s2 + P2.s2;
        f3 S3 = P0.s3 + P1.s3 + P2.s3;
        f3 S4 = P0.s4 + P1.s4 + P2.s4;
        f3 S5 = P0.s5 + P1.s5 + P2.s5;
        f3 c  = cenB;

        f3 m2S1 = splat3(-2.f) * S1;
        f3 m4S1 = splat3(-4.f) * S1;
        f3 m2S2 = splat3(-2.f) * S2;
        f3 m4S2 = splat3(-4.f) * S2;
        f3 s6S2 = splat3( 6.f) * S2;
        f3 m4S3 = splat3(-4.f) * S3;
        f3 s6S3 = splat3( 6.f) * S3;
        f3 m4S4 = splat3(-4.f) * S4;

        // M2 = S2 - 2c S1 + 27c^2 ; M4 = S4 - 4c S3 + 6c^2 S2 - 4c^3 S1 + 27c^4
        f3 M2 = fma3(c, fmas(c, 27.f, m2S1), S2);
        f3 M4 = fma3(c, fma3(c, fma3(c, fmas(c, 27.f, m4S1), s6S2), m4S3), S4);
        // T2 = S3 - 2c S2 + c^2 S1 ; T4 = S5 - 4c S4 + 6c^2 S3 - 4c^3 S2 + c^4 S1
        f3 T2 = fma3(c, fma3(c, S1, m2S2), S3);
        f3 T4 = fma3(c, fma3(c, fma3(c, fma3(c, S1, m4S2), s6S3), m4S4), S5);

        f3 den = fmas(M4, A2, fmas(M2, A1, splat3(27.f * A0)));
        f3 num = fmas(T4, A2, fmas(T2, A1, splat3(A0) * S1));

        // den >= ~19: reference clip(1e-8) is a no-op; fast rcp ~1ulp
        f3 r;
        r.x = num.x * __builtin_amdgcn_rcpf(den.x);
        r.y = num.y * __builtin_amdgcn_rcpf(den.y);
        r.z = num.z * __builtin_amdgcn_rcpf(den.z);

        float* __restrict__ orow = obase + (size_t)z * plane + (size_t)h * Ww + x0;
        orow[0] = r.x;
        orow[1] = r.y;
        orow[2] = r.z;

        // ---- fold plane z+2 into the window (skipped on the last step) ----
        if (dz < ZC - 1) {
            PS PN;
            process(NR, PN);        // waits on NR loads issued last iteration
            P0 = P1; P1 = P2; P2 = PN;
            cenB = cenC;
            cenC = NR[1];
            NR[0] = NN[0]; NR[1] = NN[1]; NR[2] = NN[2];
        }
    }
#undef XTAP
}

extern "C" void kernel_launch(void* const* d_in, const int* in_sizes, int n_in,
                              void* d_out, int out_size, void* d_ws, size_t ws_size,
                              hipStream_t stream)
{
    const float* vol = (const float*)d_in[0];
    float* out       = (float*)d_out;

    const int B = in_sizes[0] / (Dd * Hh * Ww);   // = 2

    dim3 grid(Hh / 4, Dd / ZC, B);   // (48, 16, 2) = 1536 blocks
    dim3 block(64, 4, 1);            // 256 threads = 4 waves, 1 wave per row
    bilateral3d_v8<<<grid, block, 0, stream>>>(vol, out);
}

// Round 3
// 88.799 us; speedup vs baseline: 1.2106x; 1.0424x over previous
//
#include <hip/hip_runtime.h>

// BilateralFilter3D 3x3x3, replicate pad, sigma_d=120, sigma_r=1.2
// (B,1,128,192,192) fp32.
//
// Round 9: one-variable change vs v8 -- weight fit order drops from
// quadratic-in-d^2 to LINEAR-in-d^2 (minimax on [0,1]):
//     w = B0 + B1*d^2,  B0=0.9936566, B1=-0.2933516, |err| <= 0.00634
// so num/den need only power sums S1,S2,S3 (was S1..S5):
//     den = 27B0 + B1*(S2 - 2c*S1 + 27c^2)
//     num = B0*S1 + B1*(S3 - 2c*S2 + c^2*S1)
// v8 evidence: dispatch ~27.7us (dropped below the 42us harness fills in
// top-5) vs VALU floor ~8.5us / HBM floor ~12us -> still math+latency bound;
// ~206 VALU inst/z-step. This cut deletes p4/p5 rows, 2/5 XTAPs, 2/5 z-sums,
// and the M4/T4 Horner chain: ~105 inst/z-step (~35/voxel), floor ~4.5us.
// Error budget: den>=18.9 -> worst output shift ~0.005, stacked on the 2^-8
// compare floor (absmax was bit-identical 0.00390625 for v6 AND v8 -> harness
// quantization, not our error) stays ~2x under the 1.69e-2 threshold.
// Predicted: end-to-end 92.6 -> ~80-85us; dispatch ~16-20us; VGPR ~80-100;
// absmax <= ~0.01 (pass). Fallback on absmax failure: v8 (quadratic fit).

typedef float f3 __attribute__((ext_vector_type(3)));

constexpr int Dd = 128;
constexpr int Hh = 192;
constexpr int Ww = 192;
constexpr int ZC = 8;                 // z-steps per block

// linear minimax for exp(-t/(2*1.2^2)), t = d^2 in [0,1]; spatial weights
// (dev <= 1.05e-4 from 1) folded out entirely.
constexpr float B0 = 0.9936566f;
constexpr float B1 = -0.2933516f;

__device__ __forceinline__ f3 splat3(float v) { return (f3){v, v, v}; }
__device__ __forceinline__ f3 fma3(f3 a, f3 b, f3 c) {
    return __builtin_elementwise_fma(a, b, c);
}
__device__ __forceinline__ f3 fmas(f3 a, float b, f3 c) {
    return __builtin_elementwise_fma(a, splat3(b), c);
}

struct PS { f3 s1, s2, s3; };   // x-tapped, y-summed power sums

__global__ __launch_bounds__(256, 2)
void bilateral3d_v9(const float* __restrict__ vol, float* __restrict__ out)
{
    const int t  = threadIdx.x;              // lane 0..63 (== wave lane)
    const int ty = threadIdx.y;              // 0..3
    const int h  = (blockIdx.x << 2) + ty;   // 0..191
    const int z0 = blockIdx.y * ZC;          // 0,8,...,120
    const int b  = blockIdx.z;

    const size_t plane = (size_t)Hh * Ww;
    const float* __restrict__ base  = vol + (size_t)b * Dd * plane;
    float* __restrict__       obase = out + (size_t)b * Dd * plane;

    const int x0  = t * 3;                   // 3 voxels per lane, 64*3 = 192
    const int yy0 = (h > 0) ? h - 1 : 0;     // replicate via index clamp
    const int yy2 = (h < Hh - 1) ? h + 1 : Hh - 1;

    auto load_rows = [&](f3 dst[3], int z) {
        const float* __restrict__ zb = base + (size_t)z * plane + x0;
        const float* r0 = zb + (size_t)yy0 * Ww;
        const float* r1 = zb + (size_t)h   * Ww;
        const float* r2 = zb + (size_t)yy2 * Ww;
        dst[0] = (f3){r0[0], r0[1], r0[2]};
        dst[1] = (f3){r1[0], r1[1], r1[2]};
        dst[2] = (f3){r2[0], r2[1], r2[2]};
    };

    // x-tap with lane-crossing neighbors on a y-summed power row v.
    // u.x = v(x-1)+v(x)+v(x+1) etc.; lane 0 / 63 replicate (clamp).
#define XTAP(vk, ok)                                                          \
    do {                                                                      \
        f3 v = (vk);                                                          \
        float L = __shfl_up(v.z, 1);                                          \
        float R = __shfl_down(v.x, 1);                                        \
        L = (t == 0)  ? v.x : L;                                              \
        R = (t == 63) ? v.z : R;                                              \
        float t1 = v.x + v.y;                                                 \
        float t2 = v.y + v.z;                                                 \
        (ok) = (f3){L + t1, t1 + v.z, t2 + R};                                \
    } while (0)

    // raw 3 rows of one z-plane -> y+x collapsed power sums (3 f3)
    auto process = [&](const f3 r[3], PS& o) {
        f3 p2a = r[0] * r[0], p2b = r[1] * r[1], p2c = r[2] * r[2];
        f3 p3a = p2a * r[0], p3b = p2b * r[1], p3c = p2c * r[2];
        f3 v1 = r[0] + r[1] + r[2];
        f3 v2 = p2a + p2b + p2c;
        f3 v3 = p3a + p3b + p3c;
        XTAP(v1, o.s1);
        XTAP(v2, o.s2);
        XTAP(v3, o.s3);
    };

    PS P0, P1, P2;           // planes z-1, z, z+1
    f3 cenB, cenC;           // raw center rows of planes z, z+1
    f3 NR[3];                // raw rows of plane z+2 (in flight -> next step)
    {
        f3 Ra[3], Rb[3], Rc[3];
        load_rows(Ra, (z0 > 0) ? z0 - 1 : 0);
        load_rows(Rb, z0);
        load_rows(Rc, (z0 + 1 < Dd) ? z0 + 1 : Dd - 1);
        load_rows(NR, (z0 + 2 < Dd) ? z0 + 2 : Dd - 1);
        __builtin_amdgcn_sched_barrier(0);   // keep preamble loads batched
        process(Ra, P0);
        process(Rb, P1);
        process(Rc, P2);
        cenB = Rb[1];
        cenC = Rc[1];
    }

#pragma unroll
    for (int dz = 0; dz < ZC; ++dz) {
        const int z = z0 + dz;

        // issue loads for plane z+3 now; consumed NEXT iteration -> one full
        // iteration of latency cover.
        f3 NN[3] = { splat3(0.f), splat3(0.f), splat3(0.f) };
        if (dz < ZC - 1) {
            load_rows(NN, (z + 3 < Dd) ? z + 3 : Dd - 1);
            __builtin_amdgcn_sched_barrier(0);
        }

        // ---- combine: z-sum the plane partials, Horner in c, write out ----
        f3 S1 = P0.s1 + P1.s1 + P2.s1;
        f3 S2 = P0.s2 + P1.s2 + P2.s2;
        f3 S3 = P0.s3 + P1.s3 + P2.s3;
        f3 c  = cenB;

        f3 m2S1 = splat3(-2.f) * S1;
        f3 m2S2 = splat3(-2.f) * S2;

        // M2 = S2 - 2c S1 + 27c^2 ; T2 = S3 - 2c S2 + c^2 S1
        f3 M2 = fma3(c, fmas(c, 27.f, m2S1), S2);
        f3 T2 = fma3(c, fma3(c, S1, m2S2), S3);

        f3 den = fmas(M2, B1, splat3(27.f * B0));
        f3 num = fmas(T2, B1, splat3(B0) * S1);

        // den >= ~18.9: reference clip(1e-8) is a no-op; fast rcp ~1ulp
        f3 r;
        r.x = num.x * __builtin_amdgcn_rcpf(den.x);
        r.y = num.y * __builtin_amdgcn_rcpf(den.y);
        r.z = num.z * __builtin_amdgcn_rcpf(den.z);

        float* __restrict__ orow = obase + (size_t)z * plane + (size_t)h * Ww + x0;
        orow[0] = r.x;
        orow[1] = r.y;
        orow[2] = r.z;

        // ---- fold plane z+2 into the window (skipped on the last step) ----
        if (dz < ZC - 1) {
            PS PN;
            process(NR, PN);        // waits on NR loads issued last iteration
            P0 = P1; P1 = P2; P2 = PN;
            cenB = cenC;
            cenC = NR[1];
            NR[0] = NN[0]; NR[1] = NN[1]; NR[2] = NN[2];
        }
    }
#undef XTAP
}

extern "C" void kernel_launch(void* const* d_in, const int* in_sizes, int n_in,
                              void* d_out, int out_size, void* d_ws, size_t ws_size,
                              hipStream_t stream)
{
    const float* vol = (const float*)d_in[0];
    float* out       = (float*)d_out;

    const int B = in_sizes[0] / (Dd * Hh * Ww);   // = 2

    dim3 grid(Hh / 4, Dd / ZC, B);   // (48, 16, 2) = 1536 blocks
    dim3 block(64, 4, 1);            // 256 threads = 4 waves, 1 wave per row
    bilateral3d_v9<<<grid, block, 0, stream>>>(vol, out);
}

// Round 4
// 88.535 us; speedup vs baseline: 1.2142x; 1.0030x over previous
//
#include <hip/hip_runtime.h>

// BilateralFilter3D 3x3x3, replicate pad, sigma_d=120, sigma_r=1.2
// (B,1,128,192,192) fp32.
//
// Round 10: v9 landed at ~23.9us dispatch vs issue floor ~4.5us and HBM
// floor ~14us -> latency-exposure regime, not issue- or BW-bound. Two fixes,
// independent mechanisms:
//  (1) __launch_bounds__(256,4): v9's (256,2) let the allocator spend up to
//      256 VGPR -> 2 blocks/CU = 2 waves/SIMD; live state is only ~60-70
//      floats, so cap at 128 VGPR -> 4 blocks/CU = 16 waves/CU (50% occ),
//      doubling latency-hiding. Verify: VGPR_Count <= 128, Occupancy ~2x.
//  (2) x-tap neighbors via DPP instead of __shfl: v_mov_dpp wave_shr1/
//      wave_shl1 with bound_ctrl=0 and old=clamped-edge value replaces
//      ds_bpermute + lgkmcnt wait + cndmask with ONE VALU op, and the
//      boundary lane keeps `old` == exactly the replicate clamp. Deletes all
//      6 DS ops + 6 cndmask per z-step from the critical path. Arithmetic is
//      bit-identical to the shfl version (same adds, same order).
// Math (unchanged from v9): w = B0 + B1*d^2 linear minimax, separable box
// power sums S1,S2,S3; den = 27B0 + B1*(S2-2c*S1+27c^2);
// num = B0*S1 + B1*(S3-2c*S2+c^2*S1). den>=18.9.
// Predicted: dispatch ~13-16us, end-to-end ~78-82us, absmax 0.00390625.

typedef float f3 __attribute__((ext_vector_type(3)));

constexpr int Dd = 128;
constexpr int Hh = 192;
constexpr int Ww = 192;
constexpr int ZC = 8;                 // z-steps per block

// linear minimax for exp(-t/(2*1.2^2)), t = d^2 in [0,1]; spatial weights
// (dev <= 1.05e-4 from 1) folded out entirely.
constexpr float B0 = 0.9936566f;
constexpr float B1 = -0.2933516f;

__device__ __forceinline__ f3 splat3(float v) { return (f3){v, v, v}; }
__device__ __forceinline__ f3 fma3(f3 a, f3 b, f3 c) {
    return __builtin_elementwise_fma(a, b, c);
}
__device__ __forceinline__ f3 fmas(f3 a, float b, f3 c) {
    return __builtin_elementwise_fma(a, splat3(b), c);
}

// lane i <- lane i-1 (wave_shr1); lane 0 keeps `oldv` (replicate clamp).
__device__ __forceinline__ float dpp_from_left(float oldv, float src) {
    int o = __builtin_bit_cast(int, oldv);
    int s = __builtin_bit_cast(int, src);
    int r = __builtin_amdgcn_update_dpp(o, s, 0x138, 0xF, 0xF, false);
    return __builtin_bit_cast(float, r);
}
// lane i <- lane i+1 (wave_shl1); lane 63 keeps `oldv` (replicate clamp).
__device__ __forceinline__ float dpp_from_right(float oldv, float src) {
    int o = __builtin_bit_cast(int, oldv);
    int s = __builtin_bit_cast(int, src);
    int r = __builtin_amdgcn_update_dpp(o, s, 0x130, 0xF, 0xF, false);
    return __builtin_bit_cast(float, r);
}

struct PS { f3 s1, s2, s3; };   // x-tapped, y-summed power sums

__global__ __launch_bounds__(256, 4)
void bilateral3d_v10(const float* __restrict__ vol, float* __restrict__ out)
{
    const int t  = threadIdx.x;              // lane 0..63 (== wave lane)
    const int ty = threadIdx.y;              // 0..3
    const int h  = (blockIdx.x << 2) + ty;   // 0..191
    const int z0 = blockIdx.y * ZC;          // 0,8,...,120
    const int b  = blockIdx.z;

    const size_t plane = (size_t)Hh * Ww;
    const float* __restrict__ base  = vol + (size_t)b * Dd * plane;
    float* __restrict__       obase = out + (size_t)b * Dd * plane;

    const int x0  = t * 3;                   // 3 voxels per lane, 64*3 = 192
    const int yy0 = (h > 0) ? h - 1 : 0;     // replicate via index clamp
    const int yy2 = (h < Hh - 1) ? h + 1 : Hh - 1;

    auto load_rows = [&](f3 dst[3], int z) {
        const float* __restrict__ zb = base + (size_t)z * plane + x0;
        const float* r0 = zb + (size_t)yy0 * Ww;
        const float* r1 = zb + (size_t)h   * Ww;
        const float* r2 = zb + (size_t)yy2 * Ww;
        dst[0] = (f3){r0[0], r0[1], r0[2]};
        dst[1] = (f3){r1[0], r1[1], r1[2]};
        dst[2] = (f3){r2[0], r2[1], r2[2]};
    };

    // x-tap with lane-crossing neighbors on a y-summed power row v.
    // u.x = v(x-1)+v(x)+v(x+1) etc.; boundary replicate handled by DPP `old`.
#define XTAP(vk, ok)                                                          \
    do {                                                                      \
        f3 v = (vk);                                                          \
        float L = dpp_from_left(v.x, v.z);                                    \
        float R = dpp_from_right(v.z, v.x);                                   \
        float t1 = v.x + v.y;                                                 \
        float t2 = v.y + v.z;                                                 \
        (ok) = (f3){L + t1, t1 + v.z, t2 + R};                                \
    } while (0)

    // raw 3 rows of one z-plane -> y+x collapsed power sums (3 f3)
    auto process = [&](const f3 r[3], PS& o) {
        f3 p2a = r[0] * r[0], p2b = r[1] * r[1], p2c = r[2] * r[2];
        f3 p3a = p2a * r[0], p3b = p2b * r[1], p3c = p2c * r[2];
        f3 v1 = r[0] + r[1] + r[2];
        f3 v2 = p2a + p2b + p2c;
        f3 v3 = p3a + p3b + p3c;
        XTAP(v1, o.s1);
        XTAP(v2, o.s2);
        XTAP(v3, o.s3);
    };

    PS P0, P1, P2;           // planes z-1, z, z+1
    f3 cenB, cenC;           // raw center rows of planes z, z+1
    f3 NR[3];                // raw rows of plane z+2 (in flight -> next step)
    {
        f3 Ra[3], Rb[3], Rc[3];
        load_rows(Ra, (z0 > 0) ? z0 - 1 : 0);
        load_rows(Rb, z0);
        load_rows(Rc, (z0 + 1 < Dd) ? z0 + 1 : Dd - 1);
        load_rows(NR, (z0 + 2 < Dd) ? z0 + 2 : Dd - 1);
        __builtin_amdgcn_sched_barrier(0);   // keep preamble loads batched
        process(Ra, P0);
        process(Rb, P1);
        process(Rc, P2);
        cenB = Rb[1];
        cenC = Rc[1];
    }

#pragma unroll
    for (int dz = 0; dz < ZC; ++dz) {
        const int z = z0 + dz;

        // issue loads for plane z+3 now; consumed NEXT iteration -> one full
        // iteration of latency cover.
        f3 NN[3] = { splat3(0.f), splat3(0.f), splat3(0.f) };
        if (dz < ZC - 1) {
            load_rows(NN, (z + 3 < Dd) ? z + 3 : Dd - 1);
            __builtin_amdgcn_sched_barrier(0);
        }

        // ---- combine: z-sum the plane partials, Horner in c, write out ----
        f3 S1 = P0.s1 + P1.s1 + P2.s1;
        f3 S2 = P0.s2 + P1.s2 + P2.s2;
        f3 S3 = P0.s3 + P1.s3 + P2.s3;
        f3 c  = cenB;

        f3 m2S1 = splat3(-2.f) * S1;
        f3 m2S2 = splat3(-2.f) * S2;

        // M2 = S2 - 2c S1 + 27c^2 ; T2 = S3 - 2c S2 + c^2 S1
        f3 M2 = fma3(c, fmas(c, 27.f, m2S1), S2);
        f3 T2 = fma3(c, fma3(c, S1, m2S2), S3);

        f3 den = fmas(M2, B1, splat3(27.f * B0));
        f3 num = fmas(T2, B1, splat3(B0) * S1);

        // den >= ~18.9: reference clip(1e-8) is a no-op; fast rcp ~1ulp
        f3 r;
        r.x = num.x * __builtin_amdgcn_rcpf(den.x);
        r.y = num.y * __builtin_amdgcn_rcpf(den.y);
        r.z = num.z * __builtin_amdgcn_rcpf(den.z);

        float* __restrict__ orow = obase + (size_t)z * plane + (size_t)h * Ww + x0;
        orow[0] = r.x;
        orow[1] = r.y;
        orow[2] = r.z;

        // ---- fold plane z+2 into the window (skipped on the last step) ----
        if (dz < ZC - 1) {
            PS PN;
            process(NR, PN);        // waits on NR loads issued last iteration
            P0 = P1; P1 = P2; P2 = PN;
            cenB = cenC;
            cenC = NR[1];
            NR[0] = NN[0]; NR[1] = NN[1]; NR[2] = NN[2];
        }
    }
#undef XTAP
}

extern "C" void kernel_launch(void* const* d_in, const int* in_sizes, int n_in,
                              void* d_out, int out_size, void* d_ws, size_t ws_size,
                              hipStream_t stream)
{
    const float* vol = (const float*)d_in[0];
    float* out       = (float*)d_out;

    const int B = in_sizes[0] / (Dd * Hh * Ww);   // = 2

    dim3 grid(Hh / 4, Dd / ZC, B);   // (48, 16, 2) = 1536 blocks
    dim3 block(64, 4, 1);            // 256 threads = 4 waves, 1 wave per row
    bilateral3d_v10<<<grid, block, 0, stream>>>(vol, out);
}